// Round 1
// baseline (87.394 us; speedup 1.0000x reference)
//
#include <hip/hip_runtime.h>
#include <math.h>

// RobotTrustModel: out[i] = trust_curve(p[i]; lambda_l, lambda_u, beta)
//   lambda_l = sigmoid(pre_lambda_l[0]); lambda_u = sigmoid(pre_lambda_u[0])
//   beta     = pre_beta[0]^2
//   if beta < -50 (never, beta>=0, but kept for fidelity):
//       smooth = 1 - (softplus(b(p-l)) - softplus(b(p-u))) / (b(u-l))
//   else:
//       piecewise = p<=l ? 1 : (p>u ? 0 : (u-p)/(u-l+1e-4))
//
// Memory-bound: 400 MB HBM traffic -> ~63 us floor at 6.3 TB/s.

__device__ __forceinline__ float softplus_f(float x) {
    // numerically stable softplus
    return x > 0.0f ? x + log1pf(expf(-x)) : log1pf(expf(x));
}

__device__ __forceinline__ float ramp_elem(float p, float l, float u, float inv) {
    return p <= l ? 1.0f : (p > u ? 0.0f : (u - p) * inv);
}

__device__ __forceinline__ float smooth_elem(float p, float l, float u, float b, float invden) {
    return 1.0f - (softplus_f(b * (p - l)) - softplus_f(b * (p - u))) * invden;
}

__global__ __launch_bounds__(256) void trust_curve_kernel(
    const float* __restrict__ p,
    const float* __restrict__ pre_beta,
    const float* __restrict__ pre_ll,
    const float* __restrict__ pre_lu,
    float* __restrict__ out,
    int n)
{
    // Scalar parameter prep (uniform across all lanes; ~10 VALU ops once/thread).
    const float pb = pre_beta[0];
    const float b  = pb * pb;
    const float l  = 1.0f / (1.0f + expf(-pre_ll[0]));
    const float u  = 1.0f / (1.0f + expf(-pre_lu[0]));

    const long long tid    = (long long)blockIdx.x * blockDim.x + threadIdx.x;
    const long long stride = (long long)gridDim.x * blockDim.x;
    const long long n4     = (long long)n >> 2;

    const float4* __restrict__ p4 = reinterpret_cast<const float4*>(p);
    float4* __restrict__ o4       = reinterpret_cast<float4*>(out);

    if (!(b < -50.0f)) {
        // Piecewise ramp branch (the one actually selected: beta = pre_beta^2 >= 0).
        const float inv = 1.0f / (u - l + 1e-4f);
        for (long long i = tid; i < n4; i += stride) {
            float4 v = p4[i];
            float4 r;
            r.x = ramp_elem(v.x, l, u, inv);
            r.y = ramp_elem(v.y, l, u, inv);
            r.z = ramp_elem(v.z, l, u, inv);
            r.w = ramp_elem(v.w, l, u, inv);
            o4[i] = r;
        }
        // tail (n % 4 != 0)
        for (long long i = (n4 << 2) + tid; i < n; i += stride) {
            out[i] = ramp_elem(p[i], l, u, inv);
        }
    } else {
        // Smooth logistic-integral branch (wave-uniform; unreachable for beta>=0).
        const float invden = 1.0f / (b * (u - l));
        for (long long i = tid; i < n4; i += stride) {
            float4 v = p4[i];
            float4 r;
            r.x = smooth_elem(v.x, l, u, b, invden);
            r.y = smooth_elem(v.y, l, u, b, invden);
            r.z = smooth_elem(v.z, l, u, b, invden);
            r.w = smooth_elem(v.w, l, u, b, invden);
            o4[i] = r;
        }
        for (long long i = (n4 << 2) + tid; i < n; i += stride) {
            out[i] = smooth_elem(p[i], l, u, b, invden);
        }
    }
}

extern "C" void kernel_launch(void* const* d_in, const int* in_sizes, int n_in,
                              void* d_out, int out_size, void* d_ws, size_t ws_size,
                              hipStream_t stream) {
    const float* bin_centers = (const float*)d_in[0];
    const float* pre_beta    = (const float*)d_in[1];
    const float* pre_ll      = (const float*)d_in[2];
    const float* pre_lu      = (const float*)d_in[3];
    float* out = (float*)d_out;
    const int n = in_sizes[0];

    // Memory-bound streaming op: cap grid at ~8 blocks/CU * 256 CUs and
    // grid-stride the rest (Guideline 11).
    const int block = 256;
    long long work = ((long long)n >> 2) + 1;
    int grid = (int)((work + block - 1) / block);
    if (grid > 2048) grid = 2048;
    if (grid < 1) grid = 1;

    trust_curve_kernel<<<grid, block, 0, stream>>>(
        bin_centers, pre_beta, pre_ll, pre_lu, out, n);
}

// Round 3
// 67.361 us; speedup vs baseline: 1.2974x; 1.2974x over previous
//
#include <hip/hip_runtime.h>
#include <math.h>

// RobotTrustModel: out[i] = trust_curve(p[i]; lambda_l, lambda_u, beta)
//   lambda_l = sigmoid(pre_lambda_l[0]); lambda_u = sigmoid(pre_lambda_u[0])
//   beta     = pre_beta[0]^2  (always >= 0, so the b < -50 smooth branch is
//   dead in practice; kept for fidelity, wave-uniform so zero divergence).
//
// Memory-bound: 200 MB read + 200 MB write, touch-once streams (> L3).
// R1: 87 us (4.6 TB/s) with grid-stride + cached loads. This round:
// non-temporal load/store (nt flag, bypass cache allocate) + flat grid
// (one float4 per thread). NOTE: __builtin_nontemporal_* needs a clang
// ext_vector_type pointer, not HIP's float4 class — hence f32x4 below.

typedef float f32x4 __attribute__((ext_vector_type(4)));

__device__ __forceinline__ float softplus_f(float x) {
    return x > 0.0f ? x + log1pf(expf(-x)) : log1pf(expf(x));
}

__device__ __forceinline__ float ramp_elem(float p, float l, float u, float inv) {
    return p <= l ? 1.0f : (p > u ? 0.0f : (u - p) * inv);
}

__device__ __forceinline__ float smooth_elem(float p, float l, float u, float b, float invden) {
    return 1.0f - (softplus_f(b * (p - l)) - softplus_f(b * (p - u))) * invden;
}

__global__ __launch_bounds__(256) void trust_curve_kernel(
    const float* __restrict__ p,
    const float* __restrict__ pre_beta,
    const float* __restrict__ pre_ll,
    const float* __restrict__ pre_lu,
    float* __restrict__ out,
    int n)
{
    // Scalar parameter prep (uniform; L2-broadcast loads, negligible).
    const float pb = pre_beta[0];
    const float b  = pb * pb;
    const float l  = 1.0f / (1.0f + expf(-pre_ll[0]));
    const float u  = 1.0f / (1.0f + expf(-pre_lu[0]));

    const long long tid = (long long)blockIdx.x * blockDim.x + threadIdx.x;
    const long long n4  = (long long)n >> 2;

    const f32x4* __restrict__ p4 = reinterpret_cast<const f32x4*>(p);
    f32x4* __restrict__ o4       = reinterpret_cast<f32x4*>(out);

    if (!(b < -50.0f)) {
        // Piecewise ramp branch (the live one: beta = pre_beta^2 >= 0).
        const float inv = 1.0f / (u - l + 1e-4f);
        if (tid < n4) {
            f32x4 v = __builtin_nontemporal_load(&p4[tid]);
            f32x4 r;
            r.x = ramp_elem(v.x, l, u, inv);
            r.y = ramp_elem(v.y, l, u, inv);
            r.z = ramp_elem(v.z, l, u, inv);
            r.w = ramp_elem(v.w, l, u, inv);
            __builtin_nontemporal_store(r, &o4[tid]);
        }
        // tail (n % 4 != 0): handled by the first n%4 threads globally
        const long long base = n4 << 2;
        if (tid < (n - base)) {
            out[base + tid] = ramp_elem(p[base + tid], l, u, inv);
        }
    } else {
        // Smooth logistic-integral branch (unreachable for beta >= 0).
        const float invden = 1.0f / (b * (u - l));
        if (tid < n4) {
            f32x4 v = __builtin_nontemporal_load(&p4[tid]);
            f32x4 r;
            r.x = smooth_elem(v.x, l, u, b, invden);
            r.y = smooth_elem(v.y, l, u, b, invden);
            r.z = smooth_elem(v.z, l, u, b, invden);
            r.w = smooth_elem(v.w, l, u, b, invden);
            __builtin_nontemporal_store(r, &o4[tid]);
        }
        const long long base = n4 << 2;
        if (tid < (n - base)) {
            out[base + tid] = smooth_elem(p[base + tid], l, u, b, invden);
        }
    }
}

extern "C" void kernel_launch(void* const* d_in, const int* in_sizes, int n_in,
                              void* d_out, int out_size, void* d_ws, size_t ws_size,
                              hipStream_t stream) {
    const float* bin_centers = (const float*)d_in[0];
    const float* pre_beta    = (const float*)d_in[1];
    const float* pre_ll      = (const float*)d_in[2];
    const float* pre_lu      = (const float*)d_in[3];
    float* out = (float*)d_out;
    const int n = in_sizes[0];

    // Flat grid: one float4 per thread (max memory-level parallelism).
    const int block = 256;
    long long n4 = ((long long)n >> 2);
    long long threads = n4 > 0 ? n4 : 1;
    // ensure enough threads also cover the scalar tail (n % 4 elements)
    long long tail = (long long)n - (n4 << 2);
    if (tail > threads) threads = tail;
    int grid = (int)((threads + block - 1) / block);
    if (grid < 1) grid = 1;

    trust_curve_kernel<<<grid, block, 0, stream>>>(
        bin_centers, pre_beta, pre_ll, pre_lu, out, n);
}